// Round 2
// baseline (2699.218 us; speedup 1.0000x reference)
//
#include <hip/hip_runtime.h>
#include <hip/hip_bf16.h>

typedef __hip_bfloat16 bf16;

#define Bn 4
#define Cn 512
#define C8n 64
#define Nn 4096
#define TJ 32

__device__ __forceinline__ float lo16(unsigned u) { return __uint_as_float(u << 16); }
__device__ __forceinline__ float hi16(unsigned u) { return __uint_as_float(u & 0xffff0000u); }

// ---------------- Q/K projection: qf[b][o][n], kf[b][o][n] (f32) ----------------
// block: (b, 32-wide n tile). LDS holds x[c=0..511][n tile] in f32 (64 KB).
// 8-wide output blocking: 4 LDS b32 reads feed 64 FMAs.
__global__ __launch_bounds__(256) void qk_proj(
    const float* __restrict__ x, const float* __restrict__ Wq, const float* __restrict__ bq,
    const float* __restrict__ Wk, const float* __restrict__ bk,
    float* __restrict__ qf, float* __restrict__ kf) {
  __shared__ float xs[Cn * 32];   // xs[c][n]
  int t = threadIdx.x;
  int b = blockIdx.x >> 7;
  int n0 = (blockIdx.x & 127) << 5;
  const float* xb = x + (size_t)b * Cn * Nn + n0;
  for (int idx = t; idx < Cn * 8; idx += 256) {
    int c = idx >> 3, w = idx & 7;
    *(float4*)(&xs[c * 32 + w * 4]) = *(const float4*)(xb + (size_t)c * Nn + w * 4);
  }
  __syncthreads();
  int n = t & 31, og = t >> 5;           // og in 0..7, owns o = og*8 .. og*8+7
  float aq[8], ak[8];
  #pragma unroll
  for (int r = 0; r < 8; ++r) { aq[r] = bq[og * 8 + r]; ak[r] = bk[og * 8 + r]; }
  const float* wqb = Wq + (size_t)(og * 8) * Cn;
  const float* wkb = Wk + (size_t)(og * 8) * Cn;
  for (int c4 = 0; c4 < Cn / 4; ++c4) {
    float x0 = xs[(c4 * 4 + 0) * 32 + n];
    float x1 = xs[(c4 * 4 + 1) * 32 + n];
    float x2 = xs[(c4 * 4 + 2) * 32 + n];
    float x3 = xs[(c4 * 4 + 3) * 32 + n];
    #pragma unroll
    for (int r = 0; r < 8; ++r) {
      float4 uq = *(const float4*)(wqb + (size_t)r * Cn + c4 * 4);
      float4 uk = *(const float4*)(wkb + (size_t)r * Cn + c4 * 4);
      aq[r] += uq.x * x0 + uq.y * x1 + uq.z * x2 + uq.w * x3;
      ak[r] += uk.x * x0 + uk.y * x1 + uk.z * x2 + uk.w * x3;
    }
  }
  #pragma unroll
  for (int r = 0; r < 8; ++r) {
    int o = og * 8 + r;
    qf[((size_t)b * C8n + o) * Nn + n0 + n] = aq[r];
    kf[((size_t)b * C8n + o) * Nn + n0 + n] = ak[r];
  }
}

// ---------------- V projection: vh[b][c][n] (bf16) ----------------
// block: (b, 32-wide n tile), computes ALL 512 output channels for that tile.
__global__ __launch_bounds__(256) void v_proj(
    const float* __restrict__ x, const float* __restrict__ Wv, const float* __restrict__ bv,
    bf16* __restrict__ vh) {
  __shared__ float xs[Cn * 32];
  int t = threadIdx.x;
  int b = blockIdx.x >> 7;
  int n0 = (blockIdx.x & 127) << 5;
  const float* xb = x + (size_t)b * Cn * Nn + n0;
  for (int idx = t; idx < Cn * 8; idx += 256) {
    int c = idx >> 3, w = idx & 7;
    *(float4*)(&xs[c * 32 + w * 4]) = *(const float4*)(xb + (size_t)c * Nn + w * 4);
  }
  __syncthreads();
  int n = t & 31, cg = t >> 5;           // cg owns out channels cg*64 .. cg*64+63
  for (int cb = 0; cb < 8; ++cb) {
    int c0r = cg * 64 + cb * 8;
    float acc[8];
    #pragma unroll
    for (int r = 0; r < 8; ++r) acc[r] = bv[c0r + r];
    const float* wb = Wv + (size_t)c0r * Cn;
    for (int c4 = 0; c4 < Cn / 4; ++c4) {
      float x0 = xs[(c4 * 4 + 0) * 32 + n];
      float x1 = xs[(c4 * 4 + 1) * 32 + n];
      float x2 = xs[(c4 * 4 + 2) * 32 + n];
      float x3 = xs[(c4 * 4 + 3) * 32 + n];
      #pragma unroll
      for (int r = 0; r < 8; ++r) {
        float4 uw = *(const float4*)(wb + (size_t)r * Cn + c4 * 4);
        acc[r] += uw.x * x0 + uw.y * x1 + uw.z * x2 + uw.w * x3;
      }
    }
    #pragma unroll
    for (int r = 0; r < 8; ++r)
      vh[((size_t)b * Cn + c0r + r) * Nn + n0 + n] = __float2bfloat16(acc[r]);
  }
}

// ---------------- flash attention + epilogue ----------------
// block = (b, 16-query tile i0). online softmax over j-tiles of 32.
__global__ __launch_bounds__(256) void attn(
    const float* __restrict__ qf, const float* __restrict__ kf, const bf16* __restrict__ vh,
    const float* __restrict__ x, const float* __restrict__ gamma, float* __restrict__ out) {
  __shared__ alignas(16) float qs[16 * 64];   // qs[ii][o]
  __shared__ alignas(16) float S[TJ * 20];    // S[jj][ii], stride 20 -> aligned float4
  __shared__ alignas(16) bf16 vt[Cn * 40];    // vt[c][jj], stride 40 bf16
  __shared__ alignas(16) float mrow[16];
  __shared__ alignas(16) float lrow[16];
  __shared__ alignas(16) float alphas[16];
  int t = threadIdx.x;
  int b = blockIdx.x >> 8;
  int i0 = (blockIdx.x & 255) << 4;
  const float* qb = qf + (size_t)b * C8n * Nn;
  const float* kb = kf + (size_t)b * C8n * Nn;
  const bf16* vb = vh + (size_t)b * Cn * Nn;

  for (int idx = t; idx < 16 * C8n; idx += 256) {
    int o = idx >> 4, ii = idx & 15;
    qs[ii * 64 + o] = qb[(size_t)o * Nn + i0 + ii];
  }
  if (t < 16) { mrow[t] = -1e30f; lrow[t] = 0.f; }

  float acc[4][8];
  #pragma unroll
  for (int k = 0; k < 4; ++k)
    #pragma unroll
    for (int ii = 0; ii < 8; ++ii) acc[k][ii] = 0.f;

  int cbase = t & 127;       // owns c = cbase + 128*k, k=0..3
  int half = t >> 7;         // owns ii = half*8 .. half*8+7
  int jj_s = t & 31, iig = t >> 5;   // score phase mapping
  int ii_r = t >> 4, g = t & 15;     // softmax phase mapping

  for (int tile = 0; tile < Nn / TJ; ++tile) {
    int j0 = tile * TJ;
    __syncthreads();  // protects vt/S from previous tile's readers (covers init too)

    // stage V tile: vt[c][jj]
    for (int idx = t; idx < Cn * (TJ / 4); idx += 256) {
      int c = idx >> 3, w = idx & 7;
      *(uint2*)(&vt[c * 40 + w * 4]) = *(const uint2*)(vb + (size_t)c * Nn + j0 + w * 4);
    }
    // scores: s[ii][jj] = sum_o q[ii][o] * k[o][j0+jj]
    {
      const float* kp = kb + j0 + jj_s;
      const float* q0 = qs + (iig * 2) * 64;
      const float* q1 = q0 + 64;
      float s0 = 0.f, s1 = 0.f;
      #pragma unroll
      for (int oc = 0; oc < 16; ++oc) {
        float k0 = kp[(size_t)(oc * 4 + 0) * Nn];
        float k1 = kp[(size_t)(oc * 4 + 1) * Nn];
        float k2 = kp[(size_t)(oc * 4 + 2) * Nn];
        float k3 = kp[(size_t)(oc * 4 + 3) * Nn];
        float4 qa = *(const float4*)(q0 + oc * 4);
        float4 qc = *(const float4*)(q1 + oc * 4);
        s0 += qa.x * k0 + qa.y * k1 + qa.z * k2 + qa.w * k3;
        s1 += qc.x * k0 + qc.y * k1 + qc.z * k2 + qc.w * k3;
      }
      S[jj_s * 20 + iig * 2 + 0] = s0;
      S[jj_s * 20 + iig * 2 + 1] = s1;
    }
    __syncthreads();

    // online softmax: 16 lanes per ii row, butterfly reduce over 16 lanes
    {
      float a = S[g * 20 + ii_r];
      float c2 = S[(g + 16) * 20 + ii_r];
      float mt = fmaxf(a, c2);
      #pragma unroll
      for (int m = 8; m >= 1; m >>= 1) mt = fmaxf(mt, __shfl_xor(mt, m, 64));
      float mold = mrow[ii_r];
      float mnew = fmaxf(mold, mt);
      float p0 = __expf(a - mnew);
      float p1 = __expf(c2 - mnew);
      S[g * 20 + ii_r] = p0;
      S[(g + 16) * 20 + ii_r] = p1;
      float ts = p0 + p1;
      #pragma unroll
      for (int m = 8; m >= 1; m >>= 1) ts += __shfl_xor(ts, m, 64);
      if (g == 0) {
        alphas[ii_r] = __expf(mold - mnew);
        mrow[ii_r] = mnew;
        lrow[ii_r] = lrow[ii_r] * __expf(mold - mnew) + ts;
      }
    }
    __syncthreads();

    // accumulate O[c][ii] += v[c][j] * p[ii][j]
    {
      float al[8];
      #pragma unroll
      for (int q = 0; q < 2; ++q) {
        float4 a4 = *(const float4*)(&alphas[half * 8 + q * 4]);
        al[q * 4 + 0] = a4.x; al[q * 4 + 1] = a4.y; al[q * 4 + 2] = a4.z; al[q * 4 + 3] = a4.w;
      }
      #pragma unroll
      for (int k = 0; k < 4; ++k)
        #pragma unroll
        for (int ii = 0; ii < 8; ++ii) acc[k][ii] *= al[ii];

      #pragma unroll
      for (int jc = 0; jc < TJ / 8; ++jc) {
        float vv[4][8];
        #pragma unroll
        for (int k = 0; k < 4; ++k) {
          uint4 u = *(const uint4*)(&vt[(cbase + 128 * k) * 40 + jc * 8]);
          vv[k][0] = lo16(u.x); vv[k][1] = hi16(u.x);
          vv[k][2] = lo16(u.y); vv[k][3] = hi16(u.y);
          vv[k][4] = lo16(u.z); vv[k][5] = hi16(u.z);
          vv[k][6] = lo16(u.w); vv[k][7] = hi16(u.w);
        }
        #pragma unroll
        for (int u = 0; u < 8; ++u) {
          int jj = jc * 8 + u;
          float4 pA = *(const float4*)(&S[jj * 20 + half * 8]);
          float4 pB = *(const float4*)(&S[jj * 20 + half * 8 + 4]);
          #pragma unroll
          for (int k = 0; k < 4; ++k) {
            acc[k][0] += vv[k][u] * pA.x;
            acc[k][1] += vv[k][u] * pA.y;
            acc[k][2] += vv[k][u] * pA.z;
            acc[k][3] += vv[k][u] * pA.w;
            acc[k][4] += vv[k][u] * pB.x;
            acc[k][5] += vv[k][u] * pB.y;
            acc[k][6] += vv[k][u] * pB.z;
            acc[k][7] += vv[k][u] * pB.w;
          }
        }
      }
    }
  }

  // epilogue: out = gamma * (O / l) + x   (f32 I/O)
  {
    float gm = gamma[0];
    float li[8];
    #pragma unroll
    for (int ii = 0; ii < 8; ++ii) li[ii] = 1.f / lrow[half * 8 + ii];
    #pragma unroll
    for (int k = 0; k < 4; ++k) {
      int c = cbase + 128 * k;
      size_t off = ((size_t)b * Cn + c) * Nn + i0 + half * 8;
      float4 xa = *(const float4*)(x + off);
      float4 xc = *(const float4*)(x + off + 4);
      float4 oa, oc;
      oa.x = gm * (acc[k][0] * li[0]) + xa.x;
      oa.y = gm * (acc[k][1] * li[1]) + xa.y;
      oa.z = gm * (acc[k][2] * li[2]) + xa.z;
      oa.w = gm * (acc[k][3] * li[3]) + xa.w;
      oc.x = gm * (acc[k][4] * li[4]) + xc.x;
      oc.y = gm * (acc[k][5] * li[5]) + xc.y;
      oc.z = gm * (acc[k][6] * li[6]) + xc.z;
      oc.w = gm * (acc[k][7] * li[7]) + xc.w;
      *(float4*)(out + off) = oa;
      *(float4*)(out + off + 4) = oc;
    }
  }
}

extern "C" void kernel_launch(void* const* d_in, const int* in_sizes, int n_in,
                              void* d_out, int out_size, void* d_ws, size_t ws_size,
                              hipStream_t stream) {
  const float* x     = (const float*)d_in[0];
  const float* Wq    = (const float*)d_in[1];
  const float* bq    = (const float*)d_in[2];
  const float* Wk    = (const float*)d_in[3];
  const float* bk    = (const float*)d_in[4];
  const float* Wv    = (const float*)d_in[5];
  const float* bv    = (const float*)d_in[6];
  const float* gamma = (const float*)d_in[7];
  float* out = (float*)d_out;

  float* qf = (float*)d_ws;                                  // 4 MB
  float* kf = qf + (size_t)Bn * C8n * Nn;                    // 4 MB
  bf16* vh  = (bf16*)(kf + (size_t)Bn * C8n * Nn);           // 16 MB

  qk_proj<<<dim3(Bn * 128), dim3(256), 0, stream>>>(x, Wq, bq, Wk, bk, qf, kf);
  v_proj<<<dim3(Bn * 128), dim3(256), 0, stream>>>(x, Wv, bv, vh);
  attn<<<dim3(Bn * 256), dim3(256), 0, stream>>>(qf, kf, vh, x, gamma, out);
}

// Round 3
// 886.286 us; speedup vs baseline: 3.0455x; 3.0455x over previous
//
#include <hip/hip_runtime.h>
#include <hip/hip_bf16.h>

typedef __hip_bfloat16 bf16;
typedef __attribute__((ext_vector_type(8))) short short8;
typedef __attribute__((ext_vector_type(4))) float fl4;

#define Bn 4
#define Cn 512
#define C8n 64
#define Nn 4096

union BfU { bf16 h; unsigned short u; };
__device__ __forceinline__ unsigned short f2b(float f) { BfU c; c.h = __float2bfloat16(f); return c.u; }
__device__ __forceinline__ float b2f_(unsigned short u) { BfU c; c.u = u; return __bfloat162float(c.h); }
__device__ __forceinline__ float lo16(unsigned u) { return __uint_as_float(u << 16); }
__device__ __forceinline__ float hi16(unsigned u) { return __uint_as_float(u & 0xffff0000u); }

#define MFMA16(a, b, c) __builtin_amdgcn_mfma_f32_16x16x32_bf16(a, b, c, 0, 0, 0)
// 16-lane-row rotate via DPP (VALU pipe, no LDS)
#define ROR1(x) __uint_as_float(__builtin_amdgcn_update_dpp(0, (int)__float_as_uint(x), 0x121, 0xF, 0xF, true))
#define ROR2(x) __uint_as_float(__builtin_amdgcn_update_dpp(0, (int)__float_as_uint(x), 0x122, 0xF, 0xF, true))
#define ROR4(x) __uint_as_float(__builtin_amdgcn_update_dpp(0, (int)__float_as_uint(x), 0x124, 0xF, 0xF, true))
#define ROR8(x) __uint_as_float(__builtin_amdgcn_update_dpp(0, (int)__float_as_uint(x), 0x128, 0xF, 0xF, true))

// ---------------- Q/K projection -> hi/lo bf16, transposed [b][n][64] ----------------
__global__ __launch_bounds__(256) void qk_proj(
    const float* __restrict__ x, const float* __restrict__ Wq, const float* __restrict__ bq,
    const float* __restrict__ Wk, const float* __restrict__ bk,
    bf16* __restrict__ qhi, bf16* __restrict__ qlo,
    bf16* __restrict__ khi, bf16* __restrict__ klo) {
  __shared__ float xs[Cn * 32];   // xs[c][n]
  int t = threadIdx.x;
  int b = blockIdx.x >> 7;
  int n0 = (blockIdx.x & 127) << 5;
  const float* xb = x + (size_t)b * Cn * Nn + n0;
  for (int idx = t; idx < Cn * 8; idx += 256) {
    int c = idx >> 3, wi = idx & 7;
    *(float4*)(&xs[c * 32 + wi * 4]) = *(const float4*)(xb + (size_t)c * Nn + wi * 4);
  }
  __syncthreads();
  int n = t & 31, og = t >> 5;           // og owns o = og*8 .. og*8+7
  float aq[8], ak[8];
  #pragma unroll
  for (int r = 0; r < 8; ++r) { aq[r] = bq[og * 8 + r]; ak[r] = bk[og * 8 + r]; }
  const float* wqb = Wq + (size_t)(og * 8) * Cn;
  const float* wkb = Wk + (size_t)(og * 8) * Cn;
  for (int c4 = 0; c4 < Cn / 4; ++c4) {
    float x0 = xs[(c4 * 4 + 0) * 32 + n];
    float x1 = xs[(c4 * 4 + 1) * 32 + n];
    float x2 = xs[(c4 * 4 + 2) * 32 + n];
    float x3 = xs[(c4 * 4 + 3) * 32 + n];
    #pragma unroll
    for (int r = 0; r < 8; ++r) {
      float4 uq = *(const float4*)(wqb + (size_t)r * Cn + c4 * 4);
      float4 uk = *(const float4*)(wkb + (size_t)r * Cn + c4 * 4);
      aq[r] += uq.x * x0 + uq.y * x1 + uq.z * x2 + uq.w * x3;
      ak[r] += uk.x * x0 + uk.y * x1 + uk.z * x2 + uk.w * x3;
    }
  }
  // hi/lo split, pack 8 bf16 -> uint4
  unsigned qh[8], ql[8], kh[8], kl[8];
  #pragma unroll
  for (int r = 0; r < 8; ++r) {
    unsigned short h = f2b(aq[r]); qh[r] = h; ql[r] = f2b(aq[r] - b2f_(h));
    unsigned short g = f2b(ak[r]); kh[r] = g; kl[r] = f2b(ak[r] - b2f_(g));
  }
  size_t row = ((size_t)b * Nn + n0 + n) * 64 + og * 8;
  uint4 u;
  u.x = qh[0] | (qh[1] << 16); u.y = qh[2] | (qh[3] << 16);
  u.z = qh[4] | (qh[5] << 16); u.w = qh[6] | (qh[7] << 16);
  *(uint4*)(qhi + row) = u;
  u.x = ql[0] | (ql[1] << 16); u.y = ql[2] | (ql[3] << 16);
  u.z = ql[4] | (ql[5] << 16); u.w = ql[6] | (ql[7] << 16);
  *(uint4*)(qlo + row) = u;
  u.x = kh[0] | (kh[1] << 16); u.y = kh[2] | (kh[3] << 16);
  u.z = kh[4] | (kh[5] << 16); u.w = kh[6] | (kh[7] << 16);
  *(uint4*)(khi + row) = u;
  u.x = kl[0] | (kl[1] << 16); u.y = kl[2] | (kl[3] << 16);
  u.z = kl[4] | (kl[5] << 16); u.w = kl[6] | (kl[7] << 16);
  *(uint4*)(klo + row) = u;
}

// ---------------- V projection: vh[b][c][n] (bf16) — unchanged from R2 ----------------
__global__ __launch_bounds__(256) void v_proj(
    const float* __restrict__ x, const float* __restrict__ Wv, const float* __restrict__ bv,
    bf16* __restrict__ vh) {
  __shared__ float xs[Cn * 32];
  int t = threadIdx.x;
  int b = blockIdx.x >> 7;
  int n0 = (blockIdx.x & 127) << 5;
  const float* xb = x + (size_t)b * Cn * Nn + n0;
  for (int idx = t; idx < Cn * 8; idx += 256) {
    int c = idx >> 3, wi = idx & 7;
    *(float4*)(&xs[c * 32 + wi * 4]) = *(const float4*)(xb + (size_t)c * Nn + wi * 4);
  }
  __syncthreads();
  int n = t & 31, cg = t >> 5;
  for (int cb = 0; cb < 8; ++cb) {
    int c0r = cg * 64 + cb * 8;
    float acc[8];
    #pragma unroll
    for (int r = 0; r < 8; ++r) acc[r] = bv[c0r + r];
    const float* wb = Wv + (size_t)c0r * Cn;
    for (int c4 = 0; c4 < Cn / 4; ++c4) {
      float x0 = xs[(c4 * 4 + 0) * 32 + n];
      float x1 = xs[(c4 * 4 + 1) * 32 + n];
      float x2 = xs[(c4 * 4 + 2) * 32 + n];
      float x3 = xs[(c4 * 4 + 3) * 32 + n];
      #pragma unroll
      for (int r = 0; r < 8; ++r) {
        float4 uw = *(const float4*)(wb + (size_t)r * Cn + c4 * 4);
        acc[r] += uw.x * x0 + uw.y * x1 + uw.z * x2 + uw.w * x3;
      }
    }
    #pragma unroll
    for (int r = 0; r < 8; ++r)
      vh[((size_t)b * Cn + c0r + r) * Nn + n0 + n] = __float2bfloat16(acc[r]);
  }
}

// ---------------- MFMA flash attention + epilogue ----------------
// 256 blocks (1/CU, XCD-swizzled), 512 threads = 8 waves.
// Q-tile 64 rows, j-tile 32. QK: wave (it=w&3, jt=w>>2) -> 16x16 subtile, hi/lo 3-term.
// PV: wave owns 64 channels (4 mtiles x 16), V A-frags direct from global (L2).
__global__ __launch_bounds__(512, 2) void attn(
    const bf16* __restrict__ qhi_g, const bf16* __restrict__ qlo_g,
    const bf16* __restrict__ khi_g, const bf16* __restrict__ klo_g,
    const bf16* __restrict__ vh, const float* __restrict__ x,
    const float* __restrict__ gamma, float* __restrict__ out) {
  __shared__ bf16 kths[2 * 32 * 72];     // [hi/lo][j][o], o-stride 72 (16B-aligned rows)
  __shared__ bf16 pt[64 * 40];           // P[i][j], j-stride 40
  __shared__ float2 pmps[2][64];         // per-jt partial (m, sum)
  __shared__ float2 msl[2][64];          // running (m, l), parity double-buffer
  __shared__ float alpha_s[64];

  int t = threadIdx.x;
  int w = t >> 6;
  int lane = t & 63;
  int col = lane & 15;
  int quad = lane >> 4;
  int it = w & 3, jt = w >> 2;

  int blk = blockIdx.x;
  int xcd = blk & 7;
  int b = xcd >> 1;
  int itile = ((xcd & 1) << 5) + (blk >> 3);
  int i0 = itile << 6;

  // Q fragments (A-operand): row i = i0 + it*16 + col, k = ks*32 + quad*8
  size_t qrow = ((size_t)b * Nn + i0 + it * 16 + col) * 64 + quad * 8;
  short8 qh0 = *(const short8*)(qhi_g + qrow);
  short8 qh1 = *(const short8*)(qhi_g + qrow + 32);
  short8 ql0 = *(const short8*)(qlo_g + qrow);
  short8 ql1 = *(const short8*)(qlo_g + qrow + 32);

  // K staging roles: threads 0-255 stage hi, 256-511 stage lo
  const bf16* ksrc = (t < 256) ? khi_g : klo_g;
  int ki = t & 255;
  int kj = ki >> 3, koc = ki & 7;
  size_t kgbase = ((size_t)b * Nn + kj) * 64 + koc * 8;
  bf16* kdst = &kths[(t < 256 ? 0 : 2304) + kj * 72 + koc * 8];
  uint4 kpre = *(const uint4*)(ksrc + kgbase);   // tile 0

  const bf16* vbase = vh + ((size_t)b * Cn + w * 64 + col) * Nn + quad * 8;

  if (t < 64) msl[0][t] = make_float2(-3.0e38f, 0.f);

  fl4 z = {0.f, 0.f, 0.f, 0.f};
  fl4 acc[4][4];
  #pragma unroll
  for (int mt = 0; mt < 4; ++mt)
    #pragma unroll
    for (int nt = 0; nt < 4; ++nt) acc[mt][nt] = z;

  for (int tile = 0; tile < 128; ++tile) {
    int j0 = tile << 5;
    int par = tile & 1;

    // ---- stage K (regs -> LDS), prefetch next K, issue V A-frag loads ----
    *(uint4*)kdst = kpre;
    const bf16* vj = vbase + j0;
    short8 va0 = *(const short8*)(vj);
    short8 va1 = *(const short8*)(vj + (size_t)16 * Nn);
    short8 va2 = *(const short8*)(vj + (size_t)32 * Nn);
    short8 va3 = *(const short8*)(vj + (size_t)48 * Nn);
    int jn = ((tile + 1) & 127) << 5;
    kpre = *(const uint4*)(ksrc + kgbase + (size_t)jn * 64);
    __syncthreads();

    // ---- QK: S subtile (it, jt), hi/lo 3-term, two chains for ILP ----
    const bf16* krow = &kths[(jt * 16 + col) * 72 + quad * 8];
    short8 kh0 = *(const short8*)(krow);
    short8 kh1 = *(const short8*)(krow + 32);
    short8 kl0 = *(const short8*)(krow + 2304);
    short8 kl1 = *(const short8*)(krow + 2304 + 32);
    fl4 s0 = MFMA16(qh0, kh0, z);
    fl4 s1 = MFMA16(qh1, kh1, z);
    s0 = MFMA16(ql0, kh0, s0);
    s1 = MFMA16(ql1, kh1, s1);
    s0 = MFMA16(qh0, kl0, s0);
    s1 = MFMA16(qh1, kl1, s1);
    fl4 sv = s0 + s1;

    // per-row (over 16 cols = 16-lane DPP rotate) max & exp-sum
    float mj[4], pp[4], sj[4];
    #pragma unroll
    for (int r = 0; r < 4; ++r) {
      float m = sv[r];
      m = fmaxf(m, ROR1(m)); m = fmaxf(m, ROR2(m));
      m = fmaxf(m, ROR4(m)); m = fmaxf(m, ROR8(m));
      mj[r] = m;
      float p = __expf(sv[r] - m);
      pp[r] = p;
      float s = p;
      s += ROR1(s); s += ROR2(s); s += ROR4(s); s += ROR8(s);
      sj[r] = s;
    }
    if (col == 0) {
      #pragma unroll
      for (int r = 0; r < 4; ++r)
        pmps[jt][it * 16 + quad * 4 + r] = make_float2(mj[r], sj[r]);
    }
    __syncthreads();

    // ---- stats: combine partials, write P (bf16) and state ----
    int irow = it * 16 + col;
    float2 p0 = pmps[0][irow];
    float2 p1 = pmps[1][irow];
    float2 ml = msl[par][irow];
    float mnew_l = fmaxf(fmaxf(p0.x, p1.x), ml.x);
    float mn[4];
    #pragma unroll
    for (int r = 0; r < 4; ++r) mn[r] = __shfl(mnew_l, quad * 4 + r, 64);
    #pragma unroll
    for (int r = 0; r < 4; ++r) {
      float p = pp[r] * __expf(mj[r] - mn[r]);
      pt[(it * 16 + quad * 4 + r) * 40 + jt * 16 + col] = __float2bfloat16(p);
    }
    if (jt == 0 && lane < 16) {
      float al = __expf(ml.x - mnew_l);
      float lnew = al * ml.y + p0.y * __expf(p0.x - mnew_l) + p1.y * __expf(p1.x - mnew_l);
      alpha_s[irow] = al;
      msl[par ^ 1][irow] = make_float2(mnew_l, lnew);
    }
    __syncthreads();

    // ---- PV: rescale acc, 16 independent MFMAs ----
    float av[4];
    #pragma unroll
    for (int nt = 0; nt < 4; ++nt) av[nt] = alpha_s[nt * 16 + col];
    #pragma unroll
    for (int mt = 0; mt < 4; ++mt)
      #pragma unroll
      for (int nt = 0; nt < 4; ++nt) acc[mt][nt] *= av[nt];
    short8 pb[4];
    #pragma unroll
    for (int nt = 0; nt < 4; ++nt)
      pb[nt] = *(const short8*)(&pt[(nt * 16 + col) * 40 + quad * 8]);
    #pragma unroll
    for (int nt = 0; nt < 4; ++nt) {
      acc[0][nt] = MFMA16(va0, pb[nt], acc[0][nt]);
      acc[1][nt] = MFMA16(va1, pb[nt], acc[1][nt]);
      acc[2][nt] = MFMA16(va2, pb[nt], acc[2][nt]);
      acc[3][nt] = MFMA16(va3, pb[nt], acc[3][nt]);
    }
    __syncthreads();
  }

  // ---- epilogue: out = gamma * (O/l) + x ----
  float gm = gamma[0];
  float linv[4];
  #pragma unroll
  for (int nt = 0; nt < 4; ++nt) linv[nt] = 1.f / msl[0][nt * 16 + col].y;
  #pragma unroll
  for (int mt = 0; mt < 4; ++mt) {
    int c = w * 64 + mt * 16 + quad * 4;
    #pragma unroll
    for (int r = 0; r < 4; ++r) {
      size_t rowoff = ((size_t)b * Cn + c + r) * Nn + i0;
      #pragma unroll
      for (int nt = 0; nt < 4; ++nt) {
        size_t off = rowoff + nt * 16 + col;
        out[off] = gm * (acc[mt][nt][r] * linv[nt]) + x[off];
      }
    }
  }
}

extern "C" void kernel_launch(void* const* d_in, const int* in_sizes, int n_in,
                              void* d_out, int out_size, void* d_ws, size_t ws_size,
                              hipStream_t stream) {
  const float* x     = (const float*)d_in[0];
  const float* Wq    = (const float*)d_in[1];
  const float* bq    = (const float*)d_in[2];
  const float* Wk    = (const float*)d_in[3];
  const float* bk    = (const float*)d_in[4];
  const float* Wv    = (const float*)d_in[5];
  const float* bv    = (const float*)d_in[6];
  const float* gamma = (const float*)d_in[7];
  float* out = (float*)d_out;

  size_t qkN = (size_t)Bn * Nn * 64;           // 1M elems = 2 MB each
  bf16* qhi = (bf16*)d_ws;
  bf16* qlo = qhi + qkN;
  bf16* khi = qlo + qkN;
  bf16* klo = khi + qkN;
  bf16* vh  = klo + qkN;                        // 16 MB

  qk_proj<<<dim3(Bn * 128), dim3(256), 0, stream>>>(x, Wq, bq, Wk, bk, qhi, qlo, khi, klo);
  v_proj<<<dim3(Bn * 128), dim3(256), 0, stream>>>(x, Wv, bv, vh);
  attn<<<dim3(256), dim3(512), 0, stream>>>(qhi, qlo, khi, klo, vh, x, gamma, out);
}

// Round 4
// 389.492 us; speedup vs baseline: 6.9301x; 2.2755x over previous
//
#include <hip/hip_runtime.h>
#include <hip/hip_bf16.h>

typedef __hip_bfloat16 bf16;
typedef __attribute__((ext_vector_type(8))) short short8;
typedef __attribute__((ext_vector_type(4))) float fl4;

#define Bn 4
#define Cn 512
#define C8n 64
#define Nn 4096

union BfU { bf16 h; unsigned short u; };
__device__ __forceinline__ unsigned short f2b(float f) { BfU c; c.h = __float2bfloat16(f); return c.u; }
__device__ __forceinline__ float b2f_(unsigned short u) { BfU c; c.u = u; return __bfloat162float(c.h); }

#define MFMA16(a, b, c) __builtin_amdgcn_mfma_f32_16x16x32_bf16(a, b, c, 0, 0, 0)
// 16-lane-row rotate via DPP (VALU pipe, no LDS)
#define ROR1(x) __uint_as_float(__builtin_amdgcn_update_dpp(0, (int)__float_as_uint(x), 0x121, 0xF, 0xF, true))
#define ROR2(x) __uint_as_float(__builtin_amdgcn_update_dpp(0, (int)__float_as_uint(x), 0x122, 0xF, 0xF, true))
#define ROR4(x) __uint_as_float(__builtin_amdgcn_update_dpp(0, (int)__float_as_uint(x), 0x124, 0xF, 0xF, true))
#define ROR8(x) __uint_as_float(__builtin_amdgcn_update_dpp(0, (int)__float_as_uint(x), 0x128, 0xF, 0xF, true))

// ---------------- prep: W concat -> hi/lo bf16 [640][512], bias concat ----------------
__global__ __launch_bounds__(128) void prep_w(
    const float* __restrict__ Wq, const float* __restrict__ bq,
    const float* __restrict__ Wk, const float* __restrict__ bk,
    const float* __restrict__ Wv, const float* __restrict__ bv,
    bf16* __restrict__ whi, bf16* __restrict__ wlo, float* __restrict__ bcat) {
  int row = blockIdx.x;
  int t = threadIdx.x;
  const float* src = (row < 64) ? Wq + (size_t)row * Cn
                   : (row < 128) ? Wk + (size_t)(row - 64) * Cn
                                 : Wv + (size_t)(row - 128) * Cn;
  float4 v = *(const float4*)(src + t * 4);
  unsigned short h0 = f2b(v.x), h1 = f2b(v.y), h2 = f2b(v.z), h3 = f2b(v.w);
  unsigned short l0 = f2b(v.x - b2f_(h0)), l1 = f2b(v.y - b2f_(h1));
  unsigned short l2 = f2b(v.z - b2f_(h2)), l3 = f2b(v.w - b2f_(h3));
  uint2 hu, lu;
  hu.x = h0 | ((unsigned)h1 << 16); hu.y = h2 | ((unsigned)h3 << 16);
  lu.x = l0 | ((unsigned)l1 << 16); lu.y = l2 | ((unsigned)l3 << 16);
  *(uint2*)(whi + (size_t)row * Cn + t * 4) = hu;
  *(uint2*)(wlo + (size_t)row * Cn + t * 4) = lu;
  if (t == 0)
    bcat[row] = (row < 64) ? bq[row] : (row < 128) ? bk[row - 64] : bv[row - 128];
}

// ---------------- fused QKV projection via MFMA ----------------
// block: (b, 32-position tile). 256 thr = 4 waves. M=640 channels (Q64|K64|V512),
// wave w owns m-tiles (j*4+w)*16, j=0..9. K=512 in 16 steps of 32. 3-term hi/lo.
__global__ __launch_bounds__(256, 2) void qkv_proj(
    const float* __restrict__ x, const bf16* __restrict__ whi, const bf16* __restrict__ wlo,
    const float* __restrict__ bcat,
    bf16* __restrict__ qhi, bf16* __restrict__ qlo,
    bf16* __restrict__ khi, bf16* __restrict__ klo, bf16* __restrict__ vh) {
  __shared__ float xs[Cn * 34];          // xs[cin][n], pad->34 (B-frag reads 2-way max)
  int t = threadIdx.x;
  int b = blockIdx.x >> 7;
  int n0 = (blockIdx.x & 127) << 5;

  // stage x tile (f32, coalesced float4 -> two float2 LDS writes)
  const float* xb = x + (size_t)b * Cn * Nn + n0;
  #pragma unroll
  for (int i = 0; i < 16; ++i) {
    int idx = t + i * 256;
    int cin = idx >> 3, w4 = idx & 7;
    float4 v = *(const float4*)(xb + (size_t)cin * Nn + w4 * 4);
    int base = cin * 34 + w4 * 4;
    *(float2*)(&xs[base]) = make_float2(v.x, v.y);
    *(float2*)(&xs[base + 2]) = make_float2(v.z, v.w);
  }

  int w = t >> 6, lane = t & 63, col = lane & 15, quad = lane >> 4;

  fl4 acc[10][2];
  #pragma unroll
  for (int j = 0; j < 10; ++j) {
    int m = (j * 4 + w) * 16 + quad * 4;
    fl4 bi = { bcat[m], bcat[m + 1], bcat[m + 2], bcat[m + 3] };
    acc[j][0] = bi; acc[j][1] = bi;
  }
  __syncthreads();

  for (int kk = 0; kk < 16; ++kk) {
    // A-frags (weights) from global/L2
    short8 ah[10], al[10];
    #pragma unroll
    for (int j = 0; j < 10; ++j) {
      size_t off = (size_t)(((j * 4 + w) * 16 + col)) * Cn + kk * 32 + quad * 8;
      ah[j] = *(const short8*)(whi + off);
      al[j] = *(const short8*)(wlo + off);
    }
    // B-frags (x) from LDS, convert f32 -> hi/lo bf16
    short8 bh[2], bl[2];
    #pragma unroll
    for (int ns = 0; ns < 2; ++ns) {
      #pragma unroll
      for (int jj = 0; jj < 8; ++jj) {
        float v = xs[(kk * 32 + quad * 8 + jj) * 34 + ns * 16 + col];
        unsigned short h = f2b(v);
        bh[ns][jj] = (short)h;
        bl[ns][jj] = (short)f2b(v - b2f_(h));
      }
    }
    // MFMAs: 10 m-tiles x 2 n-subtiles x 3 terms
    #pragma unroll
    for (int j = 0; j < 10; ++j) {
      #pragma unroll
      for (int ns = 0; ns < 2; ++ns) {
        acc[j][ns] = MFMA16(ah[j], bh[ns], acc[j][ns]);
        acc[j][ns] = MFMA16(al[j], bh[ns], acc[j][ns]);
        acc[j][ns] = MFMA16(ah[j], bl[ns], acc[j][ns]);
      }
    }
  }

  // ---- V epilogue: channels m>=128, direct bf16 stores ----
  #pragma unroll
  for (int j = 2; j < 10; ++j) {
    int c = (j * 4 + w) * 16 - 128 + quad * 4;
    #pragma unroll
    for (int ns = 0; ns < 2; ++ns) {
      #pragma unroll
      for (int r = 0; r < 4; ++r) {
        vh[((size_t)b * Cn + c + r) * Nn + n0 + ns * 16 + col] =
            __float2bfloat16(acc[j][ns][r]);
      }
    }
  }

  // ---- Q/K epilogue: transpose via LDS (xs is free now), pack hi/lo [b][n][64] ----
  __syncthreads();                        // all B-frag reads of xs done
  float* qbuf = xs;                       // [32][65]
  float* kbuf = xs + 32 * 65;             // [32][65]
  {
    int ch = w * 16 + quad * 4;           // j=0 -> Q ch, j=1 -> K ch (same index)
    #pragma unroll
    for (int ns = 0; ns < 2; ++ns) {
      #pragma unroll
      for (int r = 0; r < 4; ++r) {
        qbuf[(ns * 16 + col) * 65 + ch + r] = acc[0][ns][r];
        kbuf[(ns * 16 + col) * 65 + ch + r] = acc[1][ns][r];
      }
    }
  }
  __syncthreads();
  {
    int n = t >> 3, g = t & 7;
    int och = g * 8;
    size_t orow = ((size_t)b * Nn + n0 + n) * 64 + och;
    float v[8];
    unsigned short h[8], l[8];
    #pragma unroll
    for (int i = 0; i < 8; ++i) v[i] = qbuf[n * 65 + och + i];
    #pragma unroll
    for (int i = 0; i < 8; ++i) { h[i] = f2b(v[i]); l[i] = f2b(v[i] - b2f_(h[i])); }
    uint4 hu, lu;
    hu.x = h[0] | ((unsigned)h[1] << 16); hu.y = h[2] | ((unsigned)h[3] << 16);
    hu.z = h[4] | ((unsigned)h[5] << 16); hu.w = h[6] | ((unsigned)h[7] << 16);
    lu.x = l[0] | ((unsigned)l[1] << 16); lu.y = l[2] | ((unsigned)l[3] << 16);
    lu.z = l[4] | ((unsigned)l[5] << 16); lu.w = l[6] | ((unsigned)l[7] << 16);
    *(uint4*)(qhi + orow) = hu;
    *(uint4*)(qlo + orow) = lu;
    #pragma unroll
    for (int i = 0; i < 8; ++i) v[i] = kbuf[n * 65 + och + i];
    #pragma unroll
    for (int i = 0; i < 8; ++i) { h[i] = f2b(v[i]); l[i] = f2b(v[i] - b2f_(h[i])); }
    hu.x = h[0] | ((unsigned)h[1] << 16); hu.y = h[2] | ((unsigned)h[3] << 16);
    hu.z = h[4] | ((unsigned)h[5] << 16); hu.w = h[6] | ((unsigned)h[7] << 16);
    lu.x = l[0] | ((unsigned)l[1] << 16); lu.y = l[2] | ((unsigned)l[3] << 16);
    lu.z = l[4] | ((unsigned)l[5] << 16); lu.w = l[6] | ((unsigned)l[7] << 16);
    *(uint4*)(khi + orow) = hu;
    *(uint4*)(klo + orow) = lu;
  }
}

// ---------------- MFMA flash attention + epilogue (unchanged from R3) ----------------
__global__ __launch_bounds__(512, 2) void attn(
    const bf16* __restrict__ qhi_g, const bf16* __restrict__ qlo_g,
    const bf16* __restrict__ khi_g, const bf16* __restrict__ klo_g,
    const bf16* __restrict__ vh, const float* __restrict__ x,
    const float* __restrict__ gamma, float* __restrict__ out) {
  __shared__ bf16 kths[2 * 32 * 72];     // [hi/lo][j][o], o-stride 72
  __shared__ bf16 pt[64 * 40];           // P[i][j], j-stride 40
  __shared__ float2 pmps[2][64];         // per-jt partial (m, sum)
  __shared__ float2 msl[2][64];          // running (m, l), parity double-buffer
  __shared__ float alpha_s[64];

  int t = threadIdx.x;
  int w = t >> 6;
  int lane = t & 63;
  int col = lane & 15;
  int quad = lane >> 4;
  int it = w & 3, jt = w >> 2;

  int blk = blockIdx.x;
  int xcd = blk & 7;
  int b = xcd >> 1;
  int itile = ((xcd & 1) << 5) + (blk >> 3);
  int i0 = itile << 6;

  size_t qrow = ((size_t)b * Nn + i0 + it * 16 + col) * 64 + quad * 8;
  short8 qh0 = *(const short8*)(qhi_g + qrow);
  short8 qh1 = *(const short8*)(qhi_g + qrow + 32);
  short8 ql0 = *(const short8*)(qlo_g + qrow);
  short8 ql1 = *(const short8*)(qlo_g + qrow + 32);

  const bf16* ksrc = (t < 256) ? khi_g : klo_g;
  int ki = t & 255;
  int kj = ki >> 3, koc = ki & 7;
  size_t kgbase = ((size_t)b * Nn + kj) * 64 + koc * 8;
  bf16* kdst = &kths[(t < 256 ? 0 : 2304) + kj * 72 + koc * 8];
  uint4 kpre = *(const uint4*)(ksrc + kgbase);

  const bf16* vbase = vh + ((size_t)b * Cn + w * 64 + col) * Nn + quad * 8;

  if (t < 64) msl[0][t] = make_float2(-3.0e38f, 0.f);

  fl4 z = {0.f, 0.f, 0.f, 0.f};
  fl4 acc[4][4];
  #pragma unroll
  for (int mt = 0; mt < 4; ++mt)
    #pragma unroll
    for (int nt = 0; nt < 4; ++nt) acc[mt][nt] = z;

  for (int tile = 0; tile < 128; ++tile) {
    int j0 = tile << 5;
    int par = tile & 1;

    *(uint4*)kdst = kpre;
    const bf16* vj = vbase + j0;
    short8 va0 = *(const short8*)(vj);
    short8 va1 = *(const short8*)(vj + (size_t)16 * Nn);
    short8 va2 = *(const short8*)(vj + (size_t)32 * Nn);
    short8 va3 = *(const short8*)(vj + (size_t)48 * Nn);
    int jn = ((tile + 1) & 127) << 5;
    kpre = *(const uint4*)(ksrc + kgbase + (size_t)jn * 64);
    __syncthreads();

    const bf16* krow = &kths[(jt * 16 + col) * 72 + quad * 8];
    short8 kh0 = *(const short8*)(krow);
    short8 kh1 = *(const short8*)(krow + 32);
    short8 kl0 = *(const short8*)(krow + 2304);
    short8 kl1 = *(const short8*)(krow + 2304 + 32);
    fl4 s0 = MFMA16(qh0, kh0, z);
    fl4 s1 = MFMA16(qh1, kh1, z);
    s0 = MFMA16(ql0, kh0, s0);
    s1 = MFMA16(ql1, kh1, s1);
    s0 = MFMA16(qh0, kl0, s0);
    s1 = MFMA16(qh1, kl1, s1);
    fl4 sv = s0 + s1;

    float mj[4], pp[4], sj[4];
    #pragma unroll
    for (int r = 0; r < 4; ++r) {
      float m = sv[r];
      m = fmaxf(m, ROR1(m)); m = fmaxf(m, ROR2(m));
      m = fmaxf(m, ROR4(m)); m = fmaxf(m, ROR8(m));
      mj[r] = m;
      float p = __expf(sv[r] - m);
      pp[r] = p;
      float s = p;
      s += ROR1(s); s += ROR2(s); s += ROR4(s); s += ROR8(s);
      sj[r] = s;
    }
    if (col == 0) {
      #pragma unroll
      for (int r = 0; r < 4; ++r)
        pmps[jt][it * 16 + quad * 4 + r] = make_float2(mj[r], sj[r]);
    }
    __syncthreads();

    int irow = it * 16 + col;
    float2 p0 = pmps[0][irow];
    float2 p1 = pmps[1][irow];
    float2 ml = msl[par][irow];
    float mnew_l = fmaxf(fmaxf(p0.x, p1.x), ml.x);
    float mn[4];
    #pragma unroll
    for (int r = 0; r < 4; ++r) mn[r] = __shfl(mnew_l, quad * 4 + r, 64);
    #pragma unroll
    for (int r = 0; r < 4; ++r) {
      float p = pp[r] * __expf(mj[r] - mn[r]);
      pt[(it * 16 + quad * 4 + r) * 40 + jt * 16 + col] = __float2bfloat16(p);
    }
    if (jt == 0 && lane < 16) {
      float al = __expf(ml.x - mnew_l);
      float lnew = al * ml.y + p0.y * __expf(p0.x - mnew_l) + p1.y * __expf(p1.x - mnew_l);
      alpha_s[irow] = al;
      msl[par ^ 1][irow] = make_float2(mnew_l, lnew);
    }
    __syncthreads();

    float av[4];
    #pragma unroll
    for (int nt = 0; nt < 4; ++nt) av[nt] = alpha_s[nt * 16 + col];
    #pragma unroll
    for (int mt = 0; mt < 4; ++mt)
      #pragma unroll
      for (int nt = 0; nt < 4; ++nt) acc[mt][nt] *= av[nt];
    short8 pb[4];
    #pragma unroll
    for (int nt = 0; nt < 4; ++nt)
      pb[nt] = *(const short8*)(&pt[(nt * 16 + col) * 40 + quad * 8]);
    #pragma unroll
    for (int nt = 0; nt < 4; ++nt) {
      acc[0][nt] = MFMA16(va0, pb[nt], acc[0][nt]);
      acc[1][nt] = MFMA16(va1, pb[nt], acc[1][nt]);
      acc[2][nt] = MFMA16(va2, pb[nt], acc[2][nt]);
      acc[3][nt] = MFMA16(va3, pb[nt], acc[3][nt]);
    }
    __syncthreads();
  }

  float gm = gamma[0];
  float linv[4];
  #pragma unroll
  for (int nt = 0; nt < 4; ++nt) linv[nt] = 1.f / msl[0][nt * 16 + col].y;
  #pragma unroll
  for (int mt = 0; mt < 4; ++mt) {
    int c = w * 64 + mt * 16 + quad * 4;
    #pragma unroll
    for (int r = 0; r < 4; ++r) {
      size_t rowoff = ((size_t)b * Cn + c + r) * Nn + i0;
      #pragma unroll
      for (int nt = 0; nt < 4; ++nt) {
        size_t off = rowoff + nt * 16 + col;
        out[off] = gm * (acc[mt][nt][r] * linv[nt]) + x[off];
      }
    }
  }
}

extern "C" void kernel_launch(void* const* d_in, const int* in_sizes, int n_in,
                              void* d_out, int out_size, void* d_ws, size_t ws_size,
                              hipStream_t stream) {
  const float* x     = (const float*)d_in[0];
  const float* Wq    = (const float*)d_in[1];
  const float* bq    = (const float*)d_in[2];
  const float* Wk    = (const float*)d_in[3];
  const float* bk    = (const float*)d_in[4];
  const float* Wv    = (const float*)d_in[5];
  const float* bv    = (const float*)d_in[6];
  const float* gamma = (const float*)d_in[7];
  float* out = (float*)d_out;

  size_t qkN = (size_t)Bn * Nn * 64;            // 1M elems = 2 MB each
  bf16* qhi = (bf16*)d_ws;
  bf16* qlo = qhi + qkN;
  bf16* khi = qlo + qkN;
  bf16* klo = khi + qkN;
  bf16* vh  = klo + qkN;                        // 16 MB
  bf16* whi = vh + (size_t)Bn * Cn * Nn;        // 640 KB
  bf16* wlo = whi + (size_t)640 * Cn;           // 640 KB
  float* bcat = (float*)(wlo + (size_t)640 * Cn);

  prep_w<<<dim3(640), dim3(128), 0, stream>>>(Wq, bq, Wk, bk, Wv, bv, whi, wlo, bcat);
  qkv_proj<<<dim3(Bn * 128), dim3(256), 0, stream>>>(x, whi, wlo, bcat,
                                                     qhi, qlo, khi, klo, vh);
  attn<<<dim3(256), dim3(512), 0, stream>>>(qhi, qlo, khi, klo, vh, x, gamma, out);
}

// Round 5
// 314.020 us; speedup vs baseline: 8.5957x; 1.2403x over previous
//
#include <hip/hip_runtime.h>
#include <hip/hip_bf16.h>

typedef __hip_bfloat16 bf16;
typedef __attribute__((ext_vector_type(8))) short short8;
typedef __attribute__((ext_vector_type(4))) float fl4;

#define Bn 4
#define Cn 512
#define C8n 64
#define Nn 4096
#define XKS 536   // qkv LDS k-stride (bf16): 512+24 -> <=2-way banks, 16B-aligned rows

union BfU { bf16 h; unsigned short u; };
__device__ __forceinline__ unsigned short f2b(float f) { BfU c; c.h = __float2bfloat16(f); return c.u; }
__device__ __forceinline__ float b2f_(unsigned short u) { BfU c; c.u = u; return __bfloat162float(c.h); }

#define MFMA16(a, b, c) __builtin_amdgcn_mfma_f32_16x16x32_bf16(a, b, c, 0, 0, 0)
// 16-lane-row rotate via DPP (VALU pipe, no LDS)
#define ROR1(x) __uint_as_float(__builtin_amdgcn_update_dpp(0, (int)__float_as_uint(x), 0x121, 0xF, 0xF, true))
#define ROR2(x) __uint_as_float(__builtin_amdgcn_update_dpp(0, (int)__float_as_uint(x), 0x122, 0xF, 0xF, true))
#define ROR4(x) __uint_as_float(__builtin_amdgcn_update_dpp(0, (int)__float_as_uint(x), 0x124, 0xF, 0xF, true))
#define ROR8(x) __uint_as_float(__builtin_amdgcn_update_dpp(0, (int)__float_as_uint(x), 0x128, 0xF, 0xF, true))

// ---------------- prep: W concat -> hi/lo bf16 [640][512], bias concat ----------------
__global__ __launch_bounds__(128) void prep_w(
    const float* __restrict__ Wq, const float* __restrict__ bq,
    const float* __restrict__ Wk, const float* __restrict__ bk,
    const float* __restrict__ Wv, const float* __restrict__ bv,
    bf16* __restrict__ whi, bf16* __restrict__ wlo, float* __restrict__ bcat) {
  int row = blockIdx.x;
  int t = threadIdx.x;
  const float* src = (row < 64) ? Wq + (size_t)row * Cn
                   : (row < 128) ? Wk + (size_t)(row - 64) * Cn
                                 : Wv + (size_t)(row - 128) * Cn;
  float4 v = *(const float4*)(src + t * 4);
  unsigned short h0 = f2b(v.x), h1 = f2b(v.y), h2 = f2b(v.z), h3 = f2b(v.w);
  unsigned short l0 = f2b(v.x - b2f_(h0)), l1 = f2b(v.y - b2f_(h1));
  unsigned short l2 = f2b(v.z - b2f_(h2)), l3 = f2b(v.w - b2f_(h3));
  uint2 hu, lu;
  hu.x = h0 | ((unsigned)h1 << 16); hu.y = h2 | ((unsigned)h3 << 16);
  lu.x = l0 | ((unsigned)l1 << 16); lu.y = l2 | ((unsigned)l3 << 16);
  *(uint2*)(whi + (size_t)row * Cn + t * 4) = hu;
  *(uint2*)(wlo + (size_t)row * Cn + t * 4) = lu;
  if (t == 0)
    bcat[row] = (row < 64) ? bq[row] : (row < 128) ? bk[row - 64] : bv[row - 128];
}

// ---------------- fused QKV projection via MFMA ----------------
// x converted to hi/lo bf16 ONCE at staging (LDS [n][k]); per-kk B-frags are pure
// ds_read_b128 (no conversion in the K-loop).
__global__ __launch_bounds__(256, 2) void qkv_proj(
    const float* __restrict__ x, const bf16* __restrict__ whi, const bf16* __restrict__ wlo,
    const float* __restrict__ bcat,
    bf16* __restrict__ qhi, bf16* __restrict__ qlo,
    bf16* __restrict__ khi, bf16* __restrict__ klo, bf16* __restrict__ vh) {
  __shared__ bf16 xh[32 * XKS];
  __shared__ bf16 xl[32 * XKS];
  int t = threadIdx.x;
  int b = blockIdx.x >> 7;
  int n0 = (blockIdx.x & 127) << 5;

  // stage x: thread handles c-pair (2 rows) x 4 positions; hi/lo packed b32 writes
  const float* xb = x + (size_t)b * Cn * Nn + n0;
  #pragma unroll
  for (int i = 0; i < 8; ++i) {
    int idx = t + i * 256;
    int ng = idx & 7, cp = idx >> 3;
    int c0 = cp * 2;
    float4 va = *(const float4*)(xb + (size_t)c0 * Nn + ng * 4);
    float4 vb2 = *(const float4*)(xb + (size_t)(c0 + 1) * Nn + ng * 4);
    float a_[4] = { va.x, va.y, va.z, va.w };
    float b_[4] = { vb2.x, vb2.y, vb2.z, vb2.w };
    #pragma unroll
    for (int k = 0; k < 4; ++k) {
      int n = ng * 4 + k;
      unsigned short ha = f2b(a_[k]), hb = f2b(b_[k]);
      unsigned short la = f2b(a_[k] - b2f_(ha)), lb = f2b(b_[k] - b2f_(hb));
      *(unsigned*)(&xh[n * XKS + c0]) = (unsigned)ha | ((unsigned)hb << 16);
      *(unsigned*)(&xl[n * XKS + c0]) = (unsigned)la | ((unsigned)lb << 16);
    }
  }

  int w = t >> 6, lane = t & 63, col = lane & 15, quad = lane >> 4;

  fl4 acc[10][2];
  #pragma unroll
  for (int j = 0; j < 10; ++j) {
    int m = (j * 4 + w) * 16 + quad * 4;
    fl4 bi = { bcat[m], bcat[m + 1], bcat[m + 2], bcat[m + 3] };
    acc[j][0] = bi; acc[j][1] = bi;
  }
  __syncthreads();

  for (int kk = 0; kk < 16; ++kk) {
    short8 ah[10], al[10];
    #pragma unroll
    for (int j = 0; j < 10; ++j) {
      size_t off = (size_t)(((j * 4 + w) * 16 + col)) * Cn + kk * 32 + quad * 8;
      ah[j] = *(const short8*)(whi + off);
      al[j] = *(const short8*)(wlo + off);
    }
    short8 bh[2], bl[2];
    #pragma unroll
    for (int ns = 0; ns < 2; ++ns) {
      int o = (ns * 16 + col) * XKS + kk * 32 + quad * 8;
      bh[ns] = *(const short8*)(&xh[o]);
      bl[ns] = *(const short8*)(&xl[o]);
    }
    #pragma unroll
    for (int j = 0; j < 10; ++j) {
      #pragma unroll
      for (int ns = 0; ns < 2; ++ns) {
        acc[j][ns] = MFMA16(ah[j], bh[ns], acc[j][ns]);
        acc[j][ns] = MFMA16(al[j], bh[ns], acc[j][ns]);
        acc[j][ns] = MFMA16(ah[j], bl[ns], acc[j][ns]);
      }
    }
  }

  // ---- V epilogue: channels m>=128, direct bf16 stores ----
  #pragma unroll
  for (int j = 2; j < 10; ++j) {
    int c = (j * 4 + w) * 16 - 128 + quad * 4;
    #pragma unroll
    for (int ns = 0; ns < 2; ++ns) {
      #pragma unroll
      for (int r = 0; r < 4; ++r) {
        vh[((size_t)b * Cn + c + r) * Nn + n0 + ns * 16 + col] =
            __float2bfloat16(acc[j][ns][r]);
      }
    }
  }

  // ---- Q/K epilogue: transpose via LDS (reuse xh), pack hi/lo [b][n][64] ----
  __syncthreads();
  float* qbuf = (float*)xh;               // [32][65]
  float* kbuf = qbuf + 32 * 65;           // [32][65]
  {
    int ch = w * 16 + quad * 4;
    #pragma unroll
    for (int ns = 0; ns < 2; ++ns) {
      #pragma unroll
      for (int r = 0; r < 4; ++r) {
        qbuf[(ns * 16 + col) * 65 + ch + r] = acc[0][ns][r];
        kbuf[(ns * 16 + col) * 65 + ch + r] = acc[1][ns][r];
      }
    }
  }
  __syncthreads();
  {
    int n = t >> 3, g = t & 7;
    int och = g * 8;
    size_t orow = ((size_t)b * Nn + n0 + n) * 64 + och;
    float v[8];
    unsigned short h[8], l[8];
    #pragma unroll
    for (int i = 0; i < 8; ++i) v[i] = qbuf[n * 65 + och + i];
    #pragma unroll
    for (int i = 0; i < 8; ++i) { h[i] = f2b(v[i]); l[i] = f2b(v[i] - b2f_(h[i])); }
    uint4 hu, lu;
    hu.x = h[0] | ((unsigned)h[1] << 16); hu.y = h[2] | ((unsigned)h[3] << 16);
    hu.z = h[4] | ((unsigned)h[5] << 16); hu.w = h[6] | ((unsigned)h[7] << 16);
    lu.x = l[0] | ((unsigned)l[1] << 16); lu.y = l[2] | ((unsigned)l[3] << 16);
    lu.z = l[4] | ((unsigned)l[5] << 16); lu.w = l[6] | ((unsigned)l[7] << 16);
    *(uint4*)(qhi + orow) = hu;
    *(uint4*)(qlo + orow) = lu;
    #pragma unroll
    for (int i = 0; i < 8; ++i) v[i] = kbuf[n * 65 + och + i];
    #pragma unroll
    for (int i = 0; i < 8; ++i) { h[i] = f2b(v[i]); l[i] = f2b(v[i] - b2f_(h[i])); }
    hu.x = h[0] | ((unsigned)h[1] << 16); hu.y = h[2] | ((unsigned)h[3] << 16);
    hu.z = h[4] | ((unsigned)h[5] << 16); hu.w = h[6] | ((unsigned)h[7] << 16);
    lu.x = l[0] | ((unsigned)l[1] << 16); lu.y = l[2] | ((unsigned)l[3] << 16);
    lu.z = l[4] | ((unsigned)l[5] << 16); lu.w = l[6] | ((unsigned)l[7] << 16);
    *(uint4*)(khi + orow) = hu;
    *(uint4*)(klo + orow) = lu;
  }
}

// ---------------- MFMA flash attention: producer/consumer waves, 1 barrier/iter ----------------
// 768 thr = 12 waves. Waves 0-3 (S): QK + in-register online softmax for 16 rows each,
// write P/alpha[buf]. Waves 4-11 (O): 64 channels each; PV deferred one tile, V
// prefetched one tile ahead (single register buffer, WAR-ordered after PV).
__global__ __launch_bounds__(768, 3) void attn(
    const bf16* __restrict__ qhi_g, const bf16* __restrict__ qlo_g,
    const bf16* __restrict__ khi_g, const bf16* __restrict__ klo_g,
    const bf16* __restrict__ vh, const float* __restrict__ x,
    const float* __restrict__ gamma, float* __restrict__ out) {
  __shared__ bf16 kths[2 * 2 * 32 * 72]; // [buf][hl][j][72]
  __shared__ bf16 pt[2 * 64 * 40];       // [buf][i][j], j-stride 40
  __shared__ float alpha_s[2 * 64];
  __shared__ float lfin[64];

  int t = threadIdx.x;
  int w = t >> 6;
  int lane = t & 63;
  int col = lane & 15;
  int quad = lane >> 4;

  int blk = blockIdx.x;
  int xcd = blk & 7;
  int b = xcd >> 1;
  int itile = ((xcd & 1) << 5) + (blk >> 3);
  int i0 = itile << 6;

  fl4 z = {0.f, 0.f, 0.f, 0.f};

  // ---- K staging setup (threads 0-511: 256 hi + 256 lo) ----
  const bf16* ksrc = (t < 256) ? khi_g : klo_g;
  int hl = (t < 256) ? 0 : 1;
  int ki = t & 255, kj = ki >> 3, koc = ki & 7;
  size_t kgbase = ((size_t)b * Nn + kj) * 64 + koc * 8;
  bf16* kd = kths + hl * 2304 + kj * 72 + koc * 8;
  uint4 kpre;
  if (t < 512) {
    kpre = *(const uint4*)(ksrc + kgbase);            // tile 0
    *(uint4*)kd = kpre;                               // -> buf 0
    kpre = *(const uint4*)(ksrc + kgbase + 32 * 64);  // tile 1
  }

  // ---- S-wave state ----
  int it = w;                                          // valid for w<4
  short8 qh0, qh1, ql0, ql1;
  float mreg[4], lreg[4];
  if (w < 4) {
    size_t qrow = ((size_t)b * Nn + i0 + it * 16 + col) * 64 + quad * 8;
    qh0 = *(const short8*)(qhi_g + qrow);
    qh1 = *(const short8*)(qhi_g + qrow + 32);
    ql0 = *(const short8*)(qlo_g + qrow);
    ql1 = *(const short8*)(qlo_g + qrow + 32);
    #pragma unroll
    for (int r = 0; r < 4; ++r) { mreg[r] = -3.0e38f; lreg[r] = 0.f; }
  }

  // ---- O-wave state ----
  int ow = w - 4, ch0 = ow * 64;                       // valid for w>=4
  const bf16* vbase = vh + ((size_t)b * Cn + ch0 + col) * Nn + quad * 8;
  fl4 acc[4][4];
  #pragma unroll
  for (int mt = 0; mt < 4; ++mt)
    #pragma unroll
    for (int nt = 0; nt < 4; ++nt) acc[mt][nt] = z;
  short8 va[4];

  for (int tile = 0; tile < 128; ++tile) {
    __syncthreads();
    int buf = tile & 1;

    // stage K(tile+1) -> buf^1; prefetch K(tile+2)
    if (t < 512) {
      *(uint4*)(kd + (buf ^ 1) * 4608) = kpre;
      int jn = (tile + 2 < 128 ? tile + 2 : 127) << 5;
      kpre = *(const uint4*)(ksrc + kgbase + (size_t)jn * 64);
    }

    if (w < 4) {
      // ---- S: QK (12 MFMAs) + in-register softmax + write P/alpha[buf] ----
      const bf16* kb = kths + buf * 4608;
      const bf16* kbl = kb + 2304;
      short8 khA0 = *(const short8*)(kb + col * 72 + quad * 8);
      short8 khA1 = *(const short8*)(kb + col * 72 + quad * 8 + 32);
      short8 khB0 = *(const short8*)(kb + (16 + col) * 72 + quad * 8);
      short8 khB1 = *(const short8*)(kb + (16 + col) * 72 + quad * 8 + 32);
      short8 klA0 = *(const short8*)(kbl + col * 72 + quad * 8);
      short8 klA1 = *(const short8*)(kbl + col * 72 + quad * 8 + 32);
      short8 klB0 = *(const short8*)(kbl + (16 + col) * 72 + quad * 8);
      short8 klB1 = *(const short8*)(kbl + (16 + col) * 72 + quad * 8 + 32);
      fl4 sA = MFMA16(qh0, khA0, z);
      fl4 sB = MFMA16(qh0, khB0, z);
      sA = MFMA16(qh1, khA1, sA);
      sB = MFMA16(qh1, khB1, sB);
      sA = MFMA16(ql0, khA0, sA);
      sB = MFMA16(ql0, khB0, sB);
      sA = MFMA16(ql1, khA1, sA);
      sB = MFMA16(ql1, khB1, sB);
      sA = MFMA16(qh0, klA0, sA);
      sB = MFMA16(qh0, klB0, sB);
      sA = MFMA16(qh1, klA1, sA);
      sB = MFMA16(qh1, klB1, sB);

      #pragma unroll
      for (int r = 0; r < 4; ++r) {
        float mt_ = fmaxf(sA[r], sB[r]);
        mt_ = fmaxf(mt_, ROR1(mt_)); mt_ = fmaxf(mt_, ROR2(mt_));
        mt_ = fmaxf(mt_, ROR4(mt_)); mt_ = fmaxf(mt_, ROR8(mt_));
        float mnew = fmaxf(mreg[r], mt_);
        float al = __expf(mreg[r] - mnew);
        float pA = __expf(sA[r] - mnew);
        float pB = __expf(sB[r] - mnew);
        float s = pA + pB;
        s += ROR1(s); s += ROR2(s); s += ROR4(s); s += ROR8(s);
        lreg[r] = lreg[r] * al + s;
        mreg[r] = mnew;
        int i = it * 16 + quad * 4 + r;
        pt[buf * 2560 + i * 40 + col] = __float2bfloat16(pA);
        pt[buf * 2560 + i * 40 + 16 + col] = __float2bfloat16(pB);
        if (col == 0) alpha_s[buf * 64 + i] = al;
      }
    } else {
      // ---- O: PV(tile-1) from pt/alpha[buf^1] with va (=V(tile-1)), then va <- V(tile) ----
      if (tile > 0) {
        int pb_ = buf ^ 1;
        float av[4];
        #pragma unroll
        for (int nt = 0; nt < 4; ++nt) av[nt] = alpha_s[pb_ * 64 + nt * 16 + col];
        bool nr = (av[0] != 1.f) | (av[1] != 1.f) | (av[2] != 1.f) | (av[3] != 1.f);
        if (__ballot(nr)) {
          #pragma unroll
          for (int mt = 0; mt < 4; ++mt)
            #pragma unroll
            for (int nt = 0; nt < 4; ++nt) acc[mt][nt] *= av[nt];
        }
        short8 pb[4];
        #pragma unroll
        for (int nt = 0; nt < 4; ++nt)
          pb[nt] = *(const short8*)(&pt[pb_ * 2560 + (nt * 16 + col) * 40 + quad * 8]);
        #pragma unroll
        for (int nt = 0; nt < 4; ++nt) {
          acc[0][nt] = MFMA16(va[0], pb[nt], acc[0][nt]);
          acc[1][nt] = MFMA16(va[1], pb[nt], acc[1][nt]);
          acc[2][nt] = MFMA16(va[2], pb[nt], acc[2][nt]);
          acc[3][nt] = MFMA16(va[3], pb[nt], acc[3][nt]);
        }
      }
      // prefetch V(tile) for next iteration's PV (WAR after MFMAs above)
      const bf16* vj = vbase + (tile << 5);
      va[0] = *(const short8*)(vj);
      va[1] = *(const short8*)(vj + (size_t)16 * Nn);
      va[2] = *(const short8*)(vj + (size_t)32 * Nn);
      va[3] = *(const short8*)(vj + (size_t)48 * Nn);
    }
  }

  // ---- finalize ----
  if (w < 4 && col == 0) {
    #pragma unroll
    for (int r = 0; r < 4; ++r) lfin[it * 16 + quad * 4 + r] = lreg[r];
  }
  __syncthreads();

  if (w >= 4) {
    // PV(127) from buf 1
    float av[4];
    #pragma unroll
    for (int nt = 0; nt < 4; ++nt) av[nt] = alpha_s[64 + nt * 16 + col];
    bool nr = (av[0] != 1.f) | (av[1] != 1.f) | (av[2] != 1.f) | (av[3] != 1.f);
    if (__ballot(nr)) {
      #pragma unroll
      for (int mt = 0; mt < 4; ++mt)
        #pragma unroll
        for (int nt = 0; nt < 4; ++nt) acc[mt][nt] *= av[nt];
    }
    short8 pb[4];
    #pragma unroll
    for (int nt = 0; nt < 4; ++nt)
      pb[nt] = *(const short8*)(&pt[2560 + (nt * 16 + col) * 40 + quad * 8]);
    #pragma unroll
    for (int nt = 0; nt < 4; ++nt) {
      acc[0][nt] = MFMA16(va[0], pb[nt], acc[0][nt]);
      acc[1][nt] = MFMA16(va[1], pb[nt], acc[1][nt]);
      acc[2][nt] = MFMA16(va[2], pb[nt], acc[2][nt]);
      acc[3][nt] = MFMA16(va[3], pb[nt], acc[3][nt]);
    }

    float gm = gamma[0];
    float linv[4];
    #pragma unroll
    for (int nt = 0; nt < 4; ++nt) linv[nt] = 1.f / lfin[nt * 16 + col];
    #pragma unroll
    for (int mt = 0; mt < 4; ++mt) {
      int c = ch0 + mt * 16 + quad * 4;
      #pragma unroll
      for (int r = 0; r < 4; ++r) {
        size_t rowoff = ((size_t)b * Cn + c + r) * Nn + i0;
        #pragma unroll
        for (int nt = 0; nt < 4; ++nt) {
          size_t off = rowoff + nt * 16 + col;
          out[off] = gm * (acc[mt][nt][r] * linv[nt]) + x[off];
        }
      }
    }
  }
}

extern "C" void kernel_launch(void* const* d_in, const int* in_sizes, int n_in,
                              void* d_out, int out_size, void* d_ws, size_t ws_size,
                              hipStream_t stream) {
  const float* x     = (const float*)d_in[0];
  const float* Wq    = (const float*)d_in[1];
  const float* bq    = (const float*)d_in[2];
  const float* Wk    = (const float*)d_in[3];
  const float* bk    = (const float*)d_in[4];
  const float* Wv    = (const float*)d_in[5];
  const float* bv    = (const float*)d_in[6];
  const float* gamma = (const float*)d_in[7];
  float* out = (float*)d_out;

  size_t qkN = (size_t)Bn * Nn * 64;            // 1M elems = 2 MB each
  bf16* qhi = (bf16*)d_ws;
  bf16* qlo = qhi + qkN;
  bf16* khi = qlo + qkN;
  bf16* klo = khi + qkN;
  bf16* vh  = klo + qkN;                        // 16 MB
  bf16* whi = vh + (size_t)Bn * Cn * Nn;        // 640 KB
  bf16* wlo = whi + (size_t)640 * Cn;           // 640 KB
  float* bcat = (float*)(wlo + (size_t)640 * Cn);

  prep_w<<<dim3(640), dim3(128), 0, stream>>>(Wq, bq, Wk, bk, Wv, bv, whi, wlo, bcat);
  qkv_proj<<<dim3(Bn * 128), dim3(256), 0, stream>>>(x, whi, wlo, bcat,
                                                     qhi, qlo, khi, klo, vh);
  attn<<<dim3(256), dim3(768), 0, stream>>>(qhi, qlo, khi, klo, vh, x, gamma, out);
}